// Round 1
// baseline (294.126 us; speedup 1.0000x reference)
//
#include <hip/hip_runtime.h>
#include <cstdint>

#define Bn 64
#define Ln 512
#define Hn 768
#define Tn 16
#define Cn 8      // chunks over L
#define Sn 64     // chunk length
#define Kn 4      // K-split for GEMM
#define Kc 192    // K-slice per GEMM block (768/4)
#define Mrows (Bn*Ln)   // 32768
#define LOG16 2.7725887222397812f

// ---------------- K_A: partial GEMM, split-K, 64-row blocks, reg-prefetch dbuf ----------
// Latency-bound before (Occ 36%, VALU 17%, HBM 10%): 4 blocks/CU cap + barrier stalls.
// Now: 2048 blocks = 8/CU, launch_bounds(256,8) keeps VGPR<=64 -> 32 waves/CU; LDS
// double-buffer (2x9216B) with ONE barrier per sub-chunk; next chunk's global loads
// issue before compute so HBM latency hides under the 128 FMAs.
// k-accumulation order IDENTICAL to r2-r5 lineage (cc 0..5, j 0..7, same fmaf nest)
// -> em BIT-IDENTICAL -> tags unchanged.
__global__ __launch_bounds__(256, 8) void k_gemm_part(
    const float* __restrict__ hs, const float* __restrict__ W,
    float* __restrict__ partial, float* __restrict__ lossws) {
  int bx = blockIdx.x;
  if (bx == 0 && threadIdx.x == 0) {      // zero loss accumulator + ticket each iter
    lossws[0] = 0.f;
    ((int*)lossws)[1] = 0;
  }
  int rt = bx >> 2, s = bx & 3;
  int tid = threadIdx.x;
  int r0 = rt * 64, kb = s * Kc;
  int row = tid & 63;                      // each wave covers rows 0-63
  int t0 = ((tid >> 6) & 3) * 4;           // wave-uniform t-quarter -> W via s_load
  __shared__ float bufA[64 * 36];          // stride 36 (0 conflicts measured in r4)
  __shared__ float bufB[64 * 36];
  float acc[4] = {0.f, 0.f, 0.f, 0.f};
  int lr = tid >> 3, lj = (tid & 7) * 4;   // this thread's load slots: rows lr, lr+32
  const float* src0 = hs + (size_t)(r0 + lr) * Hn + kb + lj;
  const float* src1 = hs + (size_t)(r0 + lr + 32) * Hn + kb + lj;
  float* ld0a = &bufA[lr * 36 + lj];
  float* ld1a = &bufA[(lr + 32) * 36 + lj];
  float* ld0b = &bufB[lr * 36 + lj];
  float* ld1b = &bufB[(lr + 32) * 36 + lj];
  float4 pa = *(const float4*)(src0);
  float4 pb = *(const float4*)(src1);
  *(float4*)ld0a = pa;
  *(float4*)ld1a = pb;
  __syncthreads();
#pragma unroll
  for (int cc = 0; cc < 6; ++cc) {
    if (cc < 5) {                          // issue next chunk's loads early
      pa = *(const float4*)(src0 + (cc + 1) * 32);
      pb = *(const float4*)(src1 + (cc + 1) * 32);
    }
    const float* buf = (cc & 1) ? bufB : bufA;
    int k0 = kb + cc * 32;
#pragma unroll
    for (int j = 0; j < 8; ++j) {
      float4 a = *(const float4*)&buf[row * 36 + j * 4];
#pragma unroll
      for (int tt = 0; tt < 4; ++tt) {
        const float* w = W + (size_t)(t0 + tt) * Hn + k0 + j * 4;  // wave-uniform -> s_load
        acc[tt] = fmaf(a.x, w[0], fmaf(a.y, w[1], fmaf(a.z, w[2], fmaf(a.w, w[3], acc[tt]))));
      }
    }
    if (cc < 5) {                          // write NEXT buffer (other waves read cur) -> 1 barrier
      float* d0 = (cc & 1) ? ld0a : ld0b;
      float* d1 = (cc & 1) ? ld1a : ld1b;
      *(float4*)d0 = pa;
      *(float4*)d1 = pb;
      __syncthreads();
    }
  }
  float* dst = partial + ((size_t)s * Mrows + (r0 + row)) * Tn + t0;
  *(float4*)dst = make_float4(acc[0], acc[1], acc[2], acc[3]);
}

// ---------------- K_B: reduce+em, then ONE scan per block (split across doubled grid) ---
// blocks 0..511: reduce + denominator scan (+em global write); 512..1023: reduce +
// Viterbi scan (+hist).  Doubles reduce work (~8MB extra partial read, ~1.3us BW) but
// the two serial scan phases now run concurrently at 4 blocks/CU instead of
// back-to-back at 2 blocks/CU.  Reduce order unchanged -> em bit-identical.
__global__ __launch_bounds__(256) void k_em_scan(
    const float* __restrict__ partial, const float* __restrict__ bias,
    const int* __restrict__ mask, const float* __restrict__ trans,
    float* __restrict__ em, float* __restrict__ qmat,
    float* __restrict__ qv, uint8_t* __restrict__ hist) {
  int half = blockIdx.x >> 9, bc = blockIdx.x & 511;
  int b = bc >> 3, c = bc & 7;
  int tid = threadIdx.x, i = tid >> 4, tp = tid & 15;
  int l0 = c * Sn;
  __shared__ float ems[Sn * Tn];
  __shared__ int msk[Sn];
  __shared__ uint8_t hl[Tn * Sn * Tn];   // 16 KB (used by half 1 only)
  // phase 0: reduce partial -> em (bit-identical order: bias + s0..s3)
#pragma unroll
  for (int g = 0; g < 4; ++g) {
    int rl = (tid >> 4) + g * 16, t = tid & 15;
    int grow = bc * Sn + rl;
    float sum = bias[t];
#pragma unroll
    for (int s = 0; s < Kn; ++s) sum += partial[((size_t)s * Mrows + grow) * Tn + t];
    float mx = sum;
    mx = fmaxf(mx, __shfl_xor(mx, 1));
    mx = fmaxf(mx, __shfl_xor(mx, 2));
    mx = fmaxf(mx, __shfl_xor(mx, 4));
    mx = fmaxf(mx, __shfl_xor(mx, 8));
    float ev = sum - (mx + LOG16);
    ems[rl * Tn + t] = ev;
    if (half == 0) em[(size_t)grow * Tn + t] = ev;
  }
  if (tid < Sn) msk[tid] = mask[b * Ln + l0 + tid];
  __syncthreads();
  int lstart = (c == 0) ? 1 : l0;
  if (half == 0) {
    // denominator scan (linear space, renorm every 16)
    float etr[Tn];
#pragma unroll
    for (int t = 0; t < Tn; ++t) etr[t] = __expf(trans[t * Tn + tp]);
    float p = (tp == i) ? 1.f : 0.f;
    float logs = 0.f;
    for (int l = lstart; l < l0 + Sn; ++l) {
      float cs = __expf(ems[(l - l0) * Tn + tp]);
      float dot = 0.f;
#pragma unroll
      for (int t = 0; t < Tn; ++t) dot = fmaf(__shfl(p, t, 16), etr[t], dot);
      float pn = dot * cs;
      p = msk[l - l0] ? pn : p;
      if ((l & 15) == 15) {
        float m = p;
        m = fmaxf(m, __shfl_xor(m, 1));
        m = fmaxf(m, __shfl_xor(m, 2));
        m = fmaxf(m, __shfl_xor(m, 4));
        m = fmaxf(m, __shfl_xor(m, 8));
        p /= m;
        logs += __logf(m);
      }
    }
    qmat[(((size_t)b * Cn + c) * Tn + i) * Tn + tp] = __logf(p) + logs;
  } else {
    // Viterbi scan (max-plus) + history
    float tcol[Tn];
#pragma unroll
    for (int t = 0; t < Tn; ++t) tcol[t] = trans[t * Tn + tp];
    float v = (tp == i) ? 0.f : -1e30f;
    for (int l = lstart; l < l0 + Sn; ++l) {
      float best = -3.0e38f; int arg = 0;
#pragma unroll
      for (int t = 0; t < Tn; ++t) {      // strict > keeps FIRST max (jnp.argmax)
        float cand = __shfl(v, t, 16) + tcol[t];
        bool g = cand > best;
        arg = g ? t : arg;
        best = g ? cand : best;
      }
      v = best + ems[(l - l0) * Tn + tp];
      hl[(i * Sn + (l - l0)) * Tn + tp] = (uint8_t)arg;
    }
    qv[(((size_t)b * Cn + c) * Tn + i) * Tn + tp] = v;
    __syncthreads();
    const uint4* s4 = (const uint4*)hl;   // coalesced 16KB dump
    uint4* d4 = (uint4*)(hist + (size_t)bc * (Tn * Sn * Tn));
    for (int k = tid; k < (Tn * Sn * Tn) / 16; k += 256) d4[k] = s4[k];
  }
}

// ---------------- K_C: merged tail — viterbi+backtrack (blocks 0..63) runs
// CONCURRENTLY with numerator+denom-fold (blocks 64..127).  The two halves are
// independent; loss finalize uses device-scope atomic accumulate + ticket (the
// 64th numer block writes loss).  Accumulator zeroed by K_A each iteration.
__global__ __launch_bounds__(512) void k_tail(
    const float* __restrict__ qv, const float* __restrict__ em,
    const float* __restrict__ start, const float* __restrict__ endt,
    const uint8_t* __restrict__ hist, const int* __restrict__ labels,
    const int* __restrict__ mask, const float* __restrict__ trans,
    const float* __restrict__ qmat, float* __restrict__ lossws,
    float* __restrict__ loss_out, float* __restrict__ tags) {
  int bid = blockIdx.x, tid = threadIdx.x;
  if (bid >= Bn) {
    // ---- numerator + denominator fold -> llh contribution for b = bid-64 ----
    int b = bid - Bn;
    {
      int l = tid;                         // 512 threads = one l each
      int y = labels[b * Ln + l];
      int m = mask[b * Ln + l];
      float s;
      if (l == 0) s = start[y] + em[((size_t)b * Ln) * Tn + y];
      else s = m ? (trans[labels[b * Ln + l - 1] * Tn + y] + em[((size_t)b * Ln + l) * Tn + y]) : 0.f;
      int msum = m;
      for (int off = 32; off; off >>= 1) {
        s += __shfl_down(s, off);
        msum += __shfl_down(msum, off);
      }
      __shared__ float sw[8]; __shared__ int mw[8];
      __shared__ float snum;
      int wid = tid >> 6, ln = tid & 63;
      if (ln == 0) { sw[wid] = s; mw[wid] = msum; }
      __syncthreads();
      if (tid == 0) {
        float st = 0.f; int mt = 0;
        for (int wv = 0; wv < 8; ++wv) { st += sw[wv]; mt += mw[wv]; }
        snum = st + endt[labels[b * Ln + mt - 1]];
      }
      __syncthreads();
      if (tid < Tn) {                     // 16-lane log-space fold over chunk matrices
        int k = tid;
        float p = start[k] + em[((size_t)b * Ln) * Tn + k];
        for (int c = 0; c < Cn; ++c) {
          float vals[Tn]; float mx = -3.0e38f;
#pragma unroll
          for (int i2 = 0; i2 < Tn; ++i2) {
            float cand = __shfl(p, i2, 16) + qmat[(((size_t)b * Cn + c) * Tn + i2) * Tn + k];
            vals[i2] = cand;
            mx = fmaxf(mx, cand);
          }
          float sm = 0.f;
#pragma unroll
          for (int i2 = 0; i2 < Tn; ++i2) sm += __expf(vals[i2] - mx);
          p = mx + __logf(sm);
        }
        float x = p + endt[k];
        float mx = x;
        mx = fmaxf(mx, __shfl_xor(mx, 1));
        mx = fmaxf(mx, __shfl_xor(mx, 2));
        mx = fmaxf(mx, __shfl_xor(mx, 4));
        mx = fmaxf(mx, __shfl_xor(mx, 8));
        float e = __expf(x - mx);
        e += __shfl_xor(e, 1);
        e += __shfl_xor(e, 2);
        e += __shfl_xor(e, 4);
        e += __shfl_xor(e, 8);
        float denom = mx + __logf(e);
        if (k == 0) {
          atomicAdd(&lossws[0], snum - denom);
          __threadfence();
          int ticket = atomicAdd((int*)lossws + 1, 1);
          if (ticket == Bn - 1) {         // last numer block finalizes loss
            __threadfence();
            float total = atomicAdd(&lossws[0], 0.f);
            loss_out[0] = -total * (1.0f / Bn);
          }
        }
      }
    }
    return;
  }
  // ---- Viterbi fold + parallel backtrack for b = bid ----
  int b = bid;
  __shared__ int Bs[Cn][Tn];
  __shared__ int bnd[Cn + 1];
  if (tid < Tn) {
    int k = tid;
    float p = start[k] + em[((size_t)b * Ln) * Tn + k];
    for (int c = 0; c < Cn; ++c) {
      float best = -3.0e38f; int arg = 0;
#pragma unroll
      for (int i2 = 0; i2 < Tn; ++i2) {
        float cand = __shfl(p, i2, 16) + qv[(((size_t)b * Cn + c) * Tn + i2) * Tn + k];
        bool g = cand > best;
        arg = g ? i2 : arg;
        best = g ? cand : best;
      }
      Bs[c][k] = arg;
      p = best;
    }
    float x = p + endt[k]; int idx = k;   // first-max argmax over k
#pragma unroll
    for (int d = 1; d < 16; d <<= 1) {
      float xo = __shfl_xor(x, d);
      int io = __shfl_xor(idx, d);
      bool take = (xo > x) || (xo == x && io < idx);
      x = take ? xo : x;
      idx = take ? io : idx;
    }
    if (k == 0) bnd[Cn] = idx;
  }
  __syncthreads();
  if (tid == 0) {
    int t = bnd[Cn];
    for (int c = Cn - 1; c >= 0; --c) { t = Bs[c][t]; bnd[c] = t; }
  }
  __syncthreads();
  int w = tid >> 6, lane = tid & 63;      // wave w backtracks chunk w
  int istar = bnd[w];
  int cur = bnd[w + 1];
  int l0 = w * Sn;
  const uint4* hp = (const uint4*)(hist + ((size_t)(b * Cn + w) * Tn + istar) * (Sn * Tn));
  uint4 hh = hp[lane];
  float mytag = (lane == 63) ? (float)cur : 0.f;
  for (int l = l0 + 63; l >= l0 + 1; --l) {
    int sl = l - l0;
    unsigned w0 = __shfl((int)hh.x, sl);
    unsigned w1 = __shfl((int)hh.y, sl);
    unsigned w2 = __shfl((int)hh.z, sl);
    unsigned w3 = __shfl((int)hh.w, sl);
    unsigned word = (cur < 8) ? ((cur < 4) ? w0 : w1) : ((cur < 12) ? w2 : w3);
    cur = (int)((word >> ((cur & 3) * 8)) & 0xff);
    if (lane == sl - 1) mytag = (float)cur;
  }
  tags[(size_t)b * Ln + l0 + lane] = mytag;
}

extern "C" void kernel_launch(void* const* d_in, const int* in_sizes, int n_in,
                              void* d_out, int out_size, void* d_ws, size_t ws_size,
                              hipStream_t stream) {
  const float* hs     = (const float*)d_in[0];
  const int*   mask   = (const int*)d_in[1];
  const int*   labels = (const int*)d_in[2];
  const float* W      = (const float*)d_in[3];
  const float* bias   = (const float*)d_in[4];
  const float* start  = (const float*)d_in[5];
  const float* endt   = (const float*)d_in[6];
  const float* trans  = (const float*)d_in[7];
  float* out = (float*)d_out;

  // Workspace (~19.9 MB, NO aliasing — partial & hist concurrently live in K_B):
  //   em      @ 0          : 2,097,152
  //   qmat    @ 2,097,152  :   524,288
  //   qv      @ 2,621,440  :   524,288
  //   lossws  @ 3,145,728  :     4,096  (accum float + ticket int, zeroed by K_A)
  //   partial @ 3,149,824  : 8,388,608  (4*32768*16*4)
  //   hist    @ 11,538,432 : 8,388,608
  char* ws = (char*)d_ws;
  float*   em      = (float*)(ws);
  float*   qmat    = (float*)(ws + 2097152);
  float*   qv      = (float*)(ws + 2621440);
  float*   lossws  = (float*)(ws + 3145728);
  float*   partial = (float*)(ws + 3149824);
  uint8_t* hist    = (uint8_t*)(ws + 11538432);

  hipLaunchKernelGGL(k_gemm_part, dim3(2048), dim3(256), 0, stream, hs, W, partial, lossws);
  hipLaunchKernelGGL(k_em_scan,   dim3(1024), dim3(256), 0, stream, partial, bias, mask, trans, em, qmat, qv, hist);
  hipLaunchKernelGGL(k_tail,      dim3(128),  dim3(512), 0, stream, qv, em, start, endt, hist, labels, mask, trans, qmat, lossws, out, out + 1);
}